// Round 16
// baseline (284.614 us; speedup 1.0000x reference)
//
#include <hip/hip_runtime.h>
#include <hip/hip_fp8.h>

#define N_NODES 50000
#define N_EDGES 800000
#define DIM 128
#define NLAYERS 3
#define NGRAPH 512
#define SCAN_NB ((N_NODES + 255) / 256)   // 196
#define NBUCK   ((N_NODES + 255) / 256)   // 196 buckets of 256 nodes (dst>>8)
#define P1_CHUNK 2048
#define P1_EPT   8                         // 2048 / 256
#define P1_NB    ((N_EDGES + P1_CHUNK - 1) / P1_CHUNK)   // 391

typedef __attribute__((ext_vector_type(8)))  __bf16 bf16x8;
typedef __attribute__((ext_vector_type(16))) float  f32x16;
typedef __attribute__((ext_vector_type(2)))  float  f32x2;

union U8 { uint2 u; unsigned char b[8]; };

// 8 fp8 (e4m3, OCP on gfx950) -> 4x float2, packed HW cvt when available
__device__ inline void cvt8_pk(U8 x, f32x2* f) {
#if defined(__has_builtin) && __has_builtin(__builtin_amdgcn_cvt_pk_f32_fp8)
    f[0] = __builtin_amdgcn_cvt_pk_f32_fp8(x.u.x, false);
    f[1] = __builtin_amdgcn_cvt_pk_f32_fp8(x.u.x, true);
    f[2] = __builtin_amdgcn_cvt_pk_f32_fp8(x.u.y, false);
    f[3] = __builtin_amdgcn_cvt_pk_f32_fp8(x.u.y, true);
#else
#pragma unroll
    for (int j = 0; j < 4; ++j) {
        __hip_fp8_e4m3 a; a.__x = x.b[2 * j];
        __hip_fp8_e4m3 c; c.__x = x.b[2 * j + 1];
        f32x2 r; r[0] = (float)a; r[1] = (float)c;
        f[j] = r;
    }
#endif
}

// 8 f32 -> 8 fp8 bytes (packed HW cvt when available)
__device__ inline uint2 pack8_fp8(const float* v) {
    uint2 r;
    unsigned int* pr = (unsigned int*)&r;
#if defined(__has_builtin) && __has_builtin(__builtin_amdgcn_cvt_pk_fp8_f32)
#pragma unroll
    for (int w = 0; w < 2; ++w) {
        int o = 0;
        o = __builtin_amdgcn_cvt_pk_fp8_f32(v[4 * w + 0], v[4 * w + 1], o, false);
        o = __builtin_amdgcn_cvt_pk_fp8_f32(v[4 * w + 2], v[4 * w + 3], o, true);
        pr[w] = (unsigned int)o;
    }
#else
#pragma unroll
    for (int w = 0; w < 2; ++w) {
        unsigned int o = 0;
#pragma unroll
        for (int j = 0; j < 4; ++j) {
            __hip_fp8_e4m3 t8(v[4 * w + j]);
            o |= ((unsigned int)t8.__x) << (8 * j);
        }
        pr[w] = o;
    }
#endif
    return r;
}

// ---------------------------------------------------------------- fp32 -> bf16 cast
__global__ __launch_bounds__(256) void k_cast(const float* __restrict__ in,
                                              __bf16* __restrict__ out, int n) {
    int i = blockIdx.x * blockDim.x + threadIdx.x;
    int base = i * 8;
    if (base >= n) return;
    float4 a = *(const float4*)(in + base);
    float4 b = *(const float4*)(in + base + 4);
    bf16x8 o;
    o[0] = (__bf16)a.x; o[1] = (__bf16)a.y; o[2] = (__bf16)a.z; o[3] = (__bf16)a.w;
    o[4] = (__bf16)b.x; o[5] = (__bf16)b.y; o[6] = (__bf16)b.z; o[7] = (__bf16)b.w;
    *(bf16x8*)(out + base) = o;
}

// cast + PERMUTE weights into MFMA-fragment order:
// per layer, unit (ct, kt, lane) of 8 bf16 = W[ct*32 + (lane&31)][kt*16 + (lane>>5)*8 ..+7]
__global__ __launch_bounds__(256) void k_castW(
    const float* __restrict__ i0, const float* __restrict__ i1,
    const float* __restrict__ i2, const float* __restrict__ i3,
    __bf16* __restrict__ o0, __bf16* __restrict__ o1,
    __bf16* __restrict__ o2, __bf16* __restrict__ o3) {
    int sel = blockIdx.y;
    const float* in = (sel == 0) ? i0 : (sel == 1) ? i1 : (sel == 2) ? i2 : i3;
    __bf16* out     = (sel == 0) ? o0 : (sel == 1) ? o1 : (sel == 2) ? o2 : o3;
    int i = blockIdx.x * 256 + threadIdx.x;           // unit index
    if (i >= NLAYERS * 2048) return;                   // 2048 units per 128x128 matrix
    int layer = i >> 11;
    int w = i & 2047;
    int ct = w >> 9, kt = (w >> 6) & 7, lane = w & 63;
    int row = ct * 32 + (lane & 31);
    int col = kt * 16 + (lane >> 5) * 8;
    const float* srcp = in + (size_t)layer * DIM * DIM + row * DIM + col;
    float4 a = *(const float4*)srcp;
    float4 b = *(const float4*)(srcp + 4);
    bf16x8 o;
    o[0] = (__bf16)a.x; o[1] = (__bf16)a.y; o[2] = (__bf16)a.z; o[3] = (__bf16)a.w;
    o[4] = (__bf16)b.x; o[5] = (__bf16)b.y; o[6] = (__bf16)b.z; o[7] = (__bf16)b.w;
    *(bf16x8*)(out + (size_t)i * 8) = o;
}

// ---------------------------------------------------------------- degree
__global__ __launch_bounds__(256) void k_degree(const int* __restrict__ dst,
                                                int* __restrict__ cnt) {
    int i = blockIdx.x * blockDim.x + threadIdx.x;
    if (i < N_EDGES) atomicAdd(&cnt[dst[i]], 1);
}

// ---------------------------------------------------------------- hierarchical scan
__global__ __launch_bounds__(256) void k_scan1(const int* __restrict__ cnt,
                                               int* __restrict__ off,
                                               int* __restrict__ bsum) {
    __shared__ int s[256];
    int b = blockIdx.x, t = threadIdx.x;
    int i = b * 256 + t;
    int v = (i < N_NODES) ? cnt[i] : 0;
    s[t] = v; __syncthreads();
#pragma unroll
    for (int d = 1; d < 256; d <<= 1) {
        int nv = (t >= d) ? s[t - d] : 0;
        __syncthreads();
        s[t] += nv;
        __syncthreads();
    }
    if (i < N_NODES) off[i] = s[t] - v;
    if (t == 255) bsum[b] = s[255];
}

__global__ __launch_bounds__(256) void k_scan2(const int* __restrict__ bsum,
                                               int* __restrict__ boff,
                                               int* __restrict__ offN) {
    __shared__ int s[256];
    int t = threadIdx.x;
    int v = (t < SCAN_NB) ? bsum[t] : 0;
    s[t] = v; __syncthreads();
#pragma unroll
    for (int d = 1; d < 256; d <<= 1) {
        int nv = (t >= d) ? s[t - d] : 0;
        __syncthreads();
        s[t] += nv;
        __syncthreads();
    }
    boff[t] = s[t] - v;
    if (t == 255) *offN = s[255];
}

__global__ __launch_bounds__(256) void k_scan3(int* __restrict__ off,
                                               const int* __restrict__ boff) {
    int b = blockIdx.x, t = threadIdx.x;
    int i = b * 256 + t;
    if (i < N_NODES) off[i] += boff[b];
}

// ---------------------------------------------------------------- gcursor init (bucket bases)
__global__ __launch_bounds__(256) void k_ginit(const int* __restrict__ off,
                                               int* __restrict__ gcursor) {
    int t = threadIdx.x;
    if (t < NBUCK) gcursor[t] = off[t * 256];
}

// ---------------------------------------------------------------- pass 1: LDS-staged bucket binning
__global__ __launch_bounds__(256) void k_bucket(const int* __restrict__ src,
                                                const int* __restrict__ dst,
                                                int* __restrict__ gcursor,
                                                unsigned long long* __restrict__ pairs) {
    __shared__ int lcount[256];
    __shared__ int lstart[256];
    __shared__ int lresv[256];
    __shared__ unsigned long long stage[P1_CHUNK];   // 16 KB
    int t = threadIdx.x;
    int base = blockIdx.x * P1_CHUNK;
    int cnt = N_EDGES - base; if (cnt > P1_CHUNK) cnt = P1_CHUNK;

    lcount[t] = 0;
    __syncthreads();

    int my_s[P1_EPT], my_d[P1_EPT], my_b[P1_EPT];
#pragma unroll
    for (int j = 0; j < P1_EPT; ++j) {
        int idx = t + j * 256;
        if (idx < cnt) {
            my_s[j] = src[base + idx];
            my_d[j] = dst[base + idx];
            my_b[j] = my_d[j] >> 8;
            atomicAdd(&lcount[my_b[j]], 1);
        } else my_b[j] = -1;
    }
    __syncthreads();

    int v = lcount[t];
    lstart[t] = v;
    __syncthreads();
#pragma unroll
    for (int d = 1; d < 256; d <<= 1) {
        int nv = (t >= d) ? lstart[t - d] : 0;
        __syncthreads();
        lstart[t] += nv;
        __syncthreads();
    }
    int excl = lstart[t] - v;
    __syncthreads();
    lstart[t] = excl;
    lresv[t] = (t < NBUCK && v > 0) ? atomicAdd(&gcursor[t], v) : 0;
    lcount[t] = 0;
    __syncthreads();

#pragma unroll
    for (int j = 0; j < P1_EPT; ++j) {
        if (my_b[j] >= 0) {
            int lpos = lstart[my_b[j]] + atomicAdd(&lcount[my_b[j]], 1);
            stage[lpos] = ((unsigned long long)(unsigned)my_d[j] << 32) | (unsigned)my_s[j];
        }
    }
    __syncthreads();

    for (int sl = t; sl < cnt; sl += 256) {
        unsigned long long pr = stage[sl];
        int d_ = (int)(pr >> 32);
        int b_ = d_ >> 8;
        int g = lresv[b_] + (sl - lstart[b_]);
        pairs[g] = pr;
    }
}

// ---------------------------------------------------------------- pass 2: bucket -> final CSR
__global__ __launch_bounds__(256) void k_csr(const unsigned long long* __restrict__ pairs,
                                             const int* __restrict__ off,
                                             int* __restrict__ src_s) {
    __shared__ int cur[256];
    int b = blockIdx.x, t = threadIdx.x;
    int nb0 = b * 256;
    int nb1 = nb0 + 256; if (nb1 > N_NODES) nb1 = N_NODES;
    int e0 = off[nb0], e1 = off[nb1];
    cur[t] = 0;
    __syncthreads();
    for (int e = e0 + t; e < e1; e += 256) {
        unsigned long long pr = pairs[e];
        int d_ = (int)(pr >> 32);
        int s_ = (int)(pr & 0xffffffffu);
        int pos = off[d_] + atomicAdd(&cur[d_ & 255], 1);
        src_s[pos] = s_;
    }
}

// ---------------------------------------------------------------- fused 4-matrix MFMA GEMM
// A staged via coalesced load into XOR-swizzled LDS; W pre-permuted (coalesced B).
// kv layout: [node][16 units of 16B], unit g = k[g*8..+7] | v[g*8..+7] (fp8).
__global__ __launch_bounds__(256) void k_gemm_fused(
    const __bf16* __restrict__ Xb,
    const __bf16* __restrict__ Wq, const __bf16* __restrict__ Wk,
    const __bf16* __restrict__ Wv, const __bf16* __restrict__ Wsk,
    const float* __restrict__ Bq, const float* __restrict__ Bk,
    const float* __restrict__ Bv, const float* __restrict__ Bs,
    __bf16* __restrict__ Oq, unsigned char* __restrict__ Okv,
    __bf16* __restrict__ Osk) {
    __shared__ uint4 At[32][16];      // 8 KB, unit u stored at u ^ (row&15)
    __shared__ float lt[4][32][33];   // wave-private transpose tiles
    int t = threadIdx.x;
    int wsel = t >> 6, l = t & 63;
    int lo5 = l & 31, hi = l >> 5;
    int row0 = blockIdx.x * 32;

    const __bf16* W = (wsel == 0) ? Wq : (wsel == 1) ? Wk : (wsel == 2) ? Wv : Wsk;
    const float*  B = (wsel == 0) ? Bq : (wsel == 1) ? Bk : (wsel == 2) ? Bv : Bs;

    // ---- stage A: block reads 8KB linearly, swizzled LDS store
    {
        int r = t >> 3;                   // 0..31
        int u0 = (t & 7) * 2;             // 0,2,..,14
        int grow = row0 + r;
        uint4 a0 = {}, a1 = {};
        if (grow < N_NODES) {
            const uint4* gp = (const uint4*)(Xb + (size_t)grow * DIM);
            a0 = gp[u0]; a1 = gp[u0 + 1];
        }
        At[r][u0 ^ (r & 15)]       = a0;
        At[r][(u0 + 1) ^ (r & 15)] = a1;
    }
    __syncthreads();

    // ---- A fragments from LDS
    bf16x8 a[8];
#pragma unroll
    for (int kt = 0; kt < 8; ++kt)
        a[kt] = *(const bf16x8*)&At[lo5][(kt * 2 + hi) ^ (lo5 & 15)];

    int rr = l >> 1, h = l & 1;           // readback: row rr, 16-col half h
    int grow = row0 + rr;
    bool rok = (grow < N_NODES);

#pragma unroll
    for (int ct = 0; ct < 4; ++ct) {
        int col0 = ct * 32;
        const bf16x8* bp = (const bf16x8*)W + (size_t)(ct * 8) * 64 + l;  // coalesced
        f32x16 acc0 = {}, acc1 = {};
#pragma unroll
        for (int kt = 0; kt < 4; ++kt) {
            acc0 = __builtin_amdgcn_mfma_f32_32x32x16_bf16(a[kt],     bp[(size_t)kt * 64],       acc0, 0, 0, 0);
            acc1 = __builtin_amdgcn_mfma_f32_32x32x16_bf16(a[kt + 4], bp[(size_t)(kt + 4) * 64], acc1, 0, 0, 0);
        }
        f32x16 acc = acc0 + acc1;

        float bias = B[col0 + lo5];
#pragma unroll
        for (int r = 0; r < 16; ++r) {
            int rl = (r & 3) + 8 * (r >> 2) + 4 * hi;
            lt[wsel][rl][lo5] = acc[r] + bias;
        }
        __syncthreads();

        float vals[16];
#pragma unroll
        for (int j = 0; j < 16; ++j) vals[j] = lt[wsel][rr][h * 16 + j];

        if (rok) {
            int gcol = col0 + h * 16;
            if (wsel == 0 || wsel == 3) {
                __bf16* O = (wsel == 0) ? Oq : Osk;
                bf16x8 o0, o1;
#pragma unroll
                for (int j = 0; j < 8; ++j) { o0[j] = (__bf16)vals[j]; o1[j] = (__bf16)vals[8 + j]; }
                bf16x8* orow = (bf16x8*)(O + (size_t)grow * DIM + gcol);
                orow[0] = o0; orow[1] = o1;
            } else {
                // interleaved kv: col c -> byte at (c>>3)*16 + (c&7) + (v? 8 : 0)
                int koff = (wsel == 2) ? 8 : 0;
                int unit = gcol >> 3;             // even
                uint2 lo8 = pack8_fp8(vals);
                uint2 hi8 = pack8_fp8(vals + 8);
                unsigned char* base = Okv + (size_t)grow * 256;
                *(uint2*)(base + unit * 16 + koff)        = lo8;
                *(uint2*)(base + (unit + 1) * 16 + koff)  = hi8;
            }
        }
        __syncthreads();   // protect LDS tile before next ct overwrites
    }
}

// ---------------------------------------------------------------- fused alpha + softmax + aggregate (+skip+relu)
// One node per WAVE; 4x16-lane groups, 4-edge unroll, ONE uint4 gather per edge
// (interleaved k|v per 16B unit), packed fp8 cvt + pk f32 math, no-max softmax.
__global__ __launch_bounds__(256) void k_edge_fused(const __bf16* __restrict__ q,
                                                    const unsigned char* __restrict__ kv,
                                                    const __bf16* __restrict__ skip,
                                                    const int* __restrict__ src_s,
                                                    const int* __restrict__ off,
                                                    float* __restrict__ xout,
                                                    __bf16* __restrict__ xb,
                                                    int wf32) {
    int t = threadIdx.x;
    int wave = t >> 6, l = t & 63;
    int n = blockIdx.x * 4 + wave;               // 50000 = 12500 * 4
    if (n >= N_NODES) return;
    int g = l >> 4, gl = l & 15;                 // 4 groups of 16 lanes
    int start = off[n], end = off[n + 1];

    const float S = 0.08838834764831845f;        // 1/sqrt(128), folded into q
    f32x2 qf[4];
    {
        bf16x8 qv = *(const bf16x8*)(q + (size_t)n * DIM + gl * 8);
#pragma unroll
        for (int j = 0; j < 4; ++j) {
            f32x2 r;
            r[0] = (float)qv[2 * j] * S;
            r[1] = (float)qv[2 * j + 1] * S;
            qf[j] = r;
        }
    }

    float denom = 0.f;
    f32x2 facc[4] = {};

    for (int e = start + g; e < end; e += 16) {  // 4 edges per iter (group stride 4)
        int s0 = src_s[e];
        bool h1 = (e + 4 < end), h2 = (e + 8 < end), h3 = (e + 12 < end);
        int s1 = h1 ? src_s[e + 4]  : s0;
        int s2 = h2 ? src_s[e + 8]  : s0;
        int s3 = h3 ? src_s[e + 12] : s0;
        uint4 r0 = *(const uint4*)(kv + (size_t)s0 * 256 + gl * 16);
        uint4 r1 = *(const uint4*)(kv + (size_t)s1 * 256 + gl * 16);
        uint4 r2 = *(const uint4*)(kv + (size_t)s2 * 256 + gl * 16);
        uint4 r3 = *(const uint4*)(kv + (size_t)s3 * 256 + gl * 16);

        U8 ku; f32x2 kf[4];
        float p0, p1, p2, p3;
        {
            ku.u = make_uint2(r0.x, r0.y); cvt8_pk(ku, kf);
            f32x2 d = qf[0]*kf[0] + qf[1]*kf[1] + qf[2]*kf[2] + qf[3]*kf[3];
            p0 = d[0] + d[1];
        }
        {
            ku.u = make_uint2(r1.x, r1.y); cvt8_pk(ku, kf);
            f32x2 d = qf[0]*kf[0] + qf[1]*kf[1] + qf[2]*kf[2] + qf[3]*kf[3];
            p1 = d[0] + d[1];
        }
        {
            ku.u = make_uint2(r2.x, r2.y); cvt8_pk(ku, kf);
            f32x2 d = qf[0]*kf[0] + qf[1]*kf[1] + qf[2]*kf[2] + qf[3]*kf[3];
            p2 = d[0] + d[1];
        }
        {
            ku.u = make_uint2(r3.x, r3.y); cvt8_pk(ku, kf);
            f32x2 d = qf[0]*kf[0] + qf[1]*kf[1] + qf[2]*kf[2] + qf[3]*kf[3];
            p3 = d[0] + d[1];
        }
        p0 += __shfl_xor(p0, 8, 16); p1 += __shfl_xor(p1, 8, 16);
        p2 += __shfl_xor(p2, 8, 16); p3 += __shfl_xor(p3, 8, 16);
        p0 += __shfl_xor(p0, 4, 16); p1 += __shfl_xor(p1, 4, 16);
        p2 += __shfl_xor(p2, 4, 16); p3 += __shfl_xor(p3, 4, 16);
        p0 += __shfl_xor(p0, 2, 16); p1 += __shfl_xor(p1, 2, 16);
        p2 += __shfl_xor(p2, 2, 16); p3 += __shfl_xor(p3, 2, 16);
        p0 += __shfl_xor(p0, 1, 16); p1 += __shfl_xor(p1, 1, 16);
        p2 += __shfl_xor(p2, 1, 16); p3 += __shfl_xor(p3, 1, 16);
        p0 = fminf(p0, 80.f);                    // overflow insurance only
        p1 = h1 ? fminf(p1, 80.f) : -INFINITY;
        p2 = h2 ? fminf(p2, 80.f) : -INFINITY;
        p3 = h3 ? fminf(p3, 80.f) : -INFINITY;

        float w0 = __expf(p0);
        float w1 = __expf(p1);                   // exp(-inf)=0 kills tail slots
        float w2 = __expf(p2);
        float w3 = __expf(p3);
        denom += (w0 + w1) + (w2 + w3);

        U8 vu; f32x2 vf[4];
        f32x2 ww;
        ww[0] = w0; ww[1] = w0;
        vu.u = make_uint2(r0.z, r0.w); cvt8_pk(vu, vf);
#pragma unroll
        for (int j = 0; j < 4; ++j) facc[j] += ww * vf[j];
        ww[0] = w1; ww[1] = w1;
        vu.u = make_uint2(r1.z, r1.w); cvt8_pk(vu, vf);
#pragma unroll
        for (int j = 0; j < 4; ++j) facc[j] += ww * vf[j];
        ww[0] = w2; ww[1] = w2;
        vu.u = make_uint2(r2.z, r2.w); cvt8_pk(vu, vf);
#pragma unroll
        for (int j = 0; j < 4; ++j) facc[j] += ww * vf[j];
        ww[0] = w3; ww[1] = w3;
        vu.u = make_uint2(r3.z, r3.w); cvt8_pk(vu, vf);
#pragma unroll
        for (int j = 0; j < 4; ++j) facc[j] += ww * vf[j];
    }

    // merge the 4 groups: plain adds
#pragma unroll
    for (int dlt = 16; dlt <= 32; dlt <<= 1) {
        denom += __shfl_xor(denom, dlt, 64);
#pragma unroll
        for (int j = 0; j < 4; ++j) {
            f32x2 o;
            o[0] = __shfl_xor(facc[j][0], dlt, 64);
            o[1] = __shfl_xor(facc[j][1], dlt, 64);
            facc[j] += o;
        }
    }
    float inv = (denom > 0.f) ? 1.f / denom : 0.f;

    if (g == 0) {
        bf16x8 sk = *(const bf16x8*)(skip + (size_t)n * DIM + gl * 8);
        float o[8];
        bf16x8 ob;
#pragma unroll
        for (int j = 0; j < 8; ++j) {
            float f = facc[j >> 1][j & 1];
            float val = fmaxf((float)sk[j] + f * inv, 0.f);
            o[j] = val; ob[j] = (__bf16)val;
        }
        if (wf32) {
            float* xrow = xout + (size_t)n * DIM + gl * 8;
            *(float4*)(xrow)     = make_float4(o[0], o[1], o[2], o[3]);
            *(float4*)(xrow + 4) = make_float4(o[4], o[5], o[6], o[7]);
        }
        *(bf16x8*)(xb + (size_t)n * DIM + gl * 8) = ob;
    }
}

// ---------------------------------------------------------------- mean pool
__global__ __launch_bounds__(256) void k_pool(const float* __restrict__ x,
                                              const int* __restrict__ batch,
                                              float* __restrict__ out) {
    __shared__ float sacc[4][DIM];
    int g = blockIdx.x;
    int t = threadIdx.x;
    int w = t >> 6, l = t & 63;
    int lo = 0, hi = N_NODES;
    while (lo < hi) { int mid = (lo + hi) >> 1; if (batch[mid] < g) lo = mid + 1; else hi = mid; }
    int s0 = lo;
    hi = N_NODES;
    while (lo < hi) { int mid = (lo + hi) >> 1; if (batch[mid] < g + 1) lo = mid + 1; else hi = mid; }
    int s1 = lo;
    float a0 = 0.f, a1 = 0.f;
    for (int n = s0 + w; n < s1; n += 4) {
        float2 xr = *(const float2*)(x + (size_t)n * DIM + l * 2);
        a0 += xr.x; a1 += xr.y;
    }
    sacc[w][l * 2] = a0; sacc[w][l * 2 + 1] = a1;
    __syncthreads();
    if (t < DIM) {
        float s = sacc[0][t] + sacc[1][t] + sacc[2][t] + sacc[3][t];
        int cnt = s1 - s0;
        out[(size_t)g * DIM + t] = s / (float)((cnt > 0) ? cnt : 1);
    }
}

// ----------------------------------------------------------------
extern "C" void kernel_launch(void* const* d_in, const int* in_sizes, int n_in,
                              void* d_out, int out_size, void* d_ws, size_t ws_size,
                              hipStream_t stream) {
    const float* x0   = (const float*)d_in[0];
    const int*  eidx  = (const int*)d_in[1];
    const int*  batch = (const int*)d_in[2];
    const float* Wq = (const float*)d_in[3];
    const float* bq = (const float*)d_in[4];
    const float* Wk = (const float*)d_in[5];
    const float* bk = (const float*)d_in[6];
    const float* Wv = (const float*)d_in[7];
    const float* bv = (const float*)d_in[8];
    const float* Ws = (const float*)d_in[9];
    const float* bs = (const float*)d_in[10];
    float* out = (float*)d_out;

    const int* src = eidx;
    const int* dst = eidx + N_EDGES;

    char* ws = (char*)d_ws;
    size_t p = 0;
    auto alloc = [&](size_t bytes) -> void* {
        void* r = ws + p;
        p = (p + bytes + 255) & ~(size_t)255;
        return r;
    };
    int*    off    = (int*)alloc((N_NODES + 1) * sizeof(int));
    int*    cnt    = (int*)alloc(N_NODES * sizeof(int));
    int*    bsum   = (int*)alloc(256 * sizeof(int));
    int*    boff   = (int*)alloc(256 * sizeof(int));
    int*    gcur   = (int*)alloc(256 * sizeof(int));
    int*    src_s  = (int*)alloc(N_EDGES * sizeof(int));
    unsigned long long* prs = (unsigned long long*)alloc((size_t)N_EDGES * 8);
    __bf16* Xb     = (__bf16*)alloc((size_t)N_NODES * DIM * sizeof(__bf16));
    __bf16* qb     = (__bf16*)alloc((size_t)N_NODES * DIM * sizeof(__bf16));
    unsigned char* kvb = (unsigned char*)alloc((size_t)N_NODES * 256);
    __bf16* skb    = (__bf16*)alloc((size_t)N_NODES * DIM * sizeof(__bf16));
    float*  s1     = (float*)alloc((size_t)N_NODES * DIM * sizeof(float));
    __bf16* Wqb    = (__bf16*)alloc((size_t)NLAYERS * DIM * DIM * sizeof(__bf16));
    __bf16* Wkb    = (__bf16*)alloc((size_t)NLAYERS * DIM * DIM * sizeof(__bf16));
    __bf16* Wvb    = (__bf16*)alloc((size_t)NLAYERS * DIM * DIM * sizeof(__bf16));
    __bf16* Wsb    = (__bf16*)alloc((size_t)NLAYERS * DIM * DIM * sizeof(__bf16));

    // ---- casts (x linear; W cast+permute into fragment order)
    {
        int nx = N_NODES * DIM;
        k_cast<<<(nx / 8 + 255) / 256, 256, 0, stream>>>(x0, Xb, nx);
        dim3 gw((NLAYERS * 2048 + 255) / 256, 4);
        k_castW<<<gw, 256, 0, stream>>>(Wq, Wk, Wv, Ws, Wqb, Wkb, Wvb, Wsb);
    }

    // ---- build CSR (degree -> scan -> LDS-staged 2-pass bucket sort)
    hipMemsetAsync(cnt, 0, N_NODES * sizeof(int), stream);
    k_degree<<<(N_EDGES + 255) / 256, 256, 0, stream>>>(dst, cnt);
    k_scan1<<<SCAN_NB, 256, 0, stream>>>(cnt, off, bsum);
    k_scan2<<<1, 256, 0, stream>>>(bsum, boff, off + N_NODES);
    k_scan3<<<SCAN_NB, 256, 0, stream>>>(off, boff);
    k_ginit<<<1, 256, 0, stream>>>(off, gcur);
    k_bucket<<<P1_NB, 256, 0, stream>>>(src, dst, gcur, prs);
    k_csr<<<NBUCK, 256, 0, stream>>>(prs, off, src_s);

    // ---- layers
    for (int l = 0; l < NLAYERS; ++l) {
        const __bf16* wq = Wqb + (size_t)l * DIM * DIM;
        const __bf16* wk = Wkb + (size_t)l * DIM * DIM;
        const __bf16* wv = Wvb + (size_t)l * DIM * DIM;
        const __bf16* wsk = Wsb + (size_t)l * DIM * DIM;
        const float* biq = bq + (size_t)l * DIM;
        const float* bik = bk + (size_t)l * DIM;
        const float* biv = bv + (size_t)l * DIM;
        const float* bis = bs + (size_t)l * DIM;

        k_gemm_fused<<<(N_NODES + 31) / 32, 256, 0, stream>>>(Xb, wq, wk, wv, wsk,
                                                              biq, bik, biv, bis,
                                                              qb, kvb, skb);
        int wf32 = (l == NLAYERS - 1) ? 1 : 0;
        k_edge_fused<<<(N_NODES + 3) / 4, 256, 0, stream>>>(qb, kvb, skb, src_s, off,
                                                            s1, Xb, wf32);
    }

    // ---- mean pool
    k_pool<<<NGRAPH, 256, 0, stream>>>(s1, batch, out);
}

// Round 17
// 272.671 us; speedup vs baseline: 1.0438x; 1.0438x over previous
//
#include <hip/hip_runtime.h>
#include <hip/hip_fp8.h>

#define N_NODES 50000
#define N_EDGES 800000
#define DIM 128
#define NLAYERS 3
#define NGRAPH 512
#define SCAN_NB ((N_NODES + 255) / 256)   // 196
#define NBUCK   ((N_NODES + 255) / 256)   // 196 buckets of 256 nodes (dst>>8)
#define P1_CHUNK 2048
#define P1_EPT   8                         // 2048 / 256
#define P1_NB    ((N_EDGES + P1_CHUNK - 1) / P1_CHUNK)   // 391

typedef __attribute__((ext_vector_type(8)))  __bf16 bf16x8;
typedef __attribute__((ext_vector_type(16))) float  f32x16;
typedef __attribute__((ext_vector_type(2)))  float  f32x2;

union U8 { uint2 u; unsigned char b[8]; };

// 8 fp8 (e4m3, OCP on gfx950) -> 4x float2, packed HW cvt when available
__device__ inline void cvt8_pk(U8 x, f32x2* f) {
#if defined(__has_builtin) && __has_builtin(__builtin_amdgcn_cvt_pk_f32_fp8)
    f[0] = __builtin_amdgcn_cvt_pk_f32_fp8(x.u.x, false);
    f[1] = __builtin_amdgcn_cvt_pk_f32_fp8(x.u.x, true);
    f[2] = __builtin_amdgcn_cvt_pk_f32_fp8(x.u.y, false);
    f[3] = __builtin_amdgcn_cvt_pk_f32_fp8(x.u.y, true);
#else
#pragma unroll
    for (int j = 0; j < 4; ++j) {
        __hip_fp8_e4m3 a; a.__x = x.b[2 * j];
        __hip_fp8_e4m3 c; c.__x = x.b[2 * j + 1];
        f32x2 r; r[0] = (float)a; r[1] = (float)c;
        f[j] = r;
    }
#endif
}

// 16 f32 -> 16 fp8 bytes (packed HW cvt when available)
__device__ inline uint4 pack16_fp8(const float* v) {
    uint4 r;
    unsigned int* pr = (unsigned int*)&r;
#if defined(__has_builtin) && __has_builtin(__builtin_amdgcn_cvt_pk_fp8_f32)
#pragma unroll
    for (int w = 0; w < 4; ++w) {
        int o = 0;
        o = __builtin_amdgcn_cvt_pk_fp8_f32(v[4 * w + 0], v[4 * w + 1], o, false);
        o = __builtin_amdgcn_cvt_pk_fp8_f32(v[4 * w + 2], v[4 * w + 3], o, true);
        pr[w] = (unsigned int)o;
    }
#else
#pragma unroll
    for (int w = 0; w < 4; ++w) {
        unsigned int o = 0;
#pragma unroll
        for (int j = 0; j < 4; ++j) {
            __hip_fp8_e4m3 t8(v[4 * w + j]);
            o |= ((unsigned int)t8.__x) << (8 * j);
        }
        pr[w] = o;
    }
#endif
    return r;
}

// ---------------------------------------------------------------- fp32 -> bf16 cast
__global__ __launch_bounds__(256) void k_cast(const float* __restrict__ in,
                                              __bf16* __restrict__ out, int n) {
    int i = blockIdx.x * blockDim.x + threadIdx.x;
    int base = i * 8;
    if (base >= n) return;
    float4 a = *(const float4*)(in + base);
    float4 b = *(const float4*)(in + base + 4);
    bf16x8 o;
    o[0] = (__bf16)a.x; o[1] = (__bf16)a.y; o[2] = (__bf16)a.z; o[3] = (__bf16)a.w;
    o[4] = (__bf16)b.x; o[5] = (__bf16)b.y; o[6] = (__bf16)b.z; o[7] = (__bf16)b.w;
    *(bf16x8*)(out + base) = o;
}

// cast + PERMUTE weights into MFMA-fragment order:
// per layer, unit (ct, kt, lane) of 8 bf16 = W[ct*32 + (lane&31)][kt*16 + (lane>>5)*8 ..+7]
__global__ __launch_bounds__(256) void k_castW(
    const float* __restrict__ i0, const float* __restrict__ i1,
    const float* __restrict__ i2, const float* __restrict__ i3,
    __bf16* __restrict__ o0, __bf16* __restrict__ o1,
    __bf16* __restrict__ o2, __bf16* __restrict__ o3) {
    int sel = blockIdx.y;
    const float* in = (sel == 0) ? i0 : (sel == 1) ? i1 : (sel == 2) ? i2 : i3;
    __bf16* out     = (sel == 0) ? o0 : (sel == 1) ? o1 : (sel == 2) ? o2 : o3;
    int i = blockIdx.x * 256 + threadIdx.x;           // unit index
    if (i >= NLAYERS * 2048) return;                   // 2048 units per 128x128 matrix
    int layer = i >> 11;
    int w = i & 2047;
    int ct = w >> 9, kt = (w >> 6) & 7, lane = w & 63;
    int row = ct * 32 + (lane & 31);
    int col = kt * 16 + (lane >> 5) * 8;
    const float* srcp = in + (size_t)layer * DIM * DIM + row * DIM + col;
    float4 a = *(const float4*)srcp;
    float4 b = *(const float4*)(srcp + 4);
    bf16x8 o;
    o[0] = (__bf16)a.x; o[1] = (__bf16)a.y; o[2] = (__bf16)a.z; o[3] = (__bf16)a.w;
    o[4] = (__bf16)b.x; o[5] = (__bf16)b.y; o[6] = (__bf16)b.z; o[7] = (__bf16)b.w;
    *(bf16x8*)(out + (size_t)i * 8) = o;
}

// ---------------------------------------------------------------- degree
__global__ __launch_bounds__(256) void k_degree(const int* __restrict__ dst,
                                                int* __restrict__ cnt) {
    int i = blockIdx.x * blockDim.x + threadIdx.x;
    if (i < N_EDGES) atomicAdd(&cnt[dst[i]], 1);
}

// ---------------------------------------------------------------- hierarchical scan
__global__ __launch_bounds__(256) void k_scan1(const int* __restrict__ cnt,
                                               int* __restrict__ off,
                                               int* __restrict__ bsum) {
    __shared__ int s[256];
    int b = blockIdx.x, t = threadIdx.x;
    int i = b * 256 + t;
    int v = (i < N_NODES) ? cnt[i] : 0;
    s[t] = v; __syncthreads();
#pragma unroll
    for (int d = 1; d < 256; d <<= 1) {
        int nv = (t >= d) ? s[t - d] : 0;
        __syncthreads();
        s[t] += nv;
        __syncthreads();
    }
    if (i < N_NODES) off[i] = s[t] - v;
    if (t == 255) bsum[b] = s[255];
}

__global__ __launch_bounds__(256) void k_scan2(const int* __restrict__ bsum,
                                               int* __restrict__ boff,
                                               int* __restrict__ offN) {
    __shared__ int s[256];
    int t = threadIdx.x;
    int v = (t < SCAN_NB) ? bsum[t] : 0;
    s[t] = v; __syncthreads();
#pragma unroll
    for (int d = 1; d < 256; d <<= 1) {
        int nv = (t >= d) ? s[t - d] : 0;
        __syncthreads();
        s[t] += nv;
        __syncthreads();
    }
    boff[t] = s[t] - v;
    if (t == 255) *offN = s[255];
}

__global__ __launch_bounds__(256) void k_scan3(int* __restrict__ off,
                                               const int* __restrict__ boff) {
    int b = blockIdx.x, t = threadIdx.x;
    int i = b * 256 + t;
    if (i < N_NODES) off[i] += boff[b];
}

// ---------------------------------------------------------------- gcursor init (bucket bases)
__global__ __launch_bounds__(256) void k_ginit(const int* __restrict__ off,
                                               int* __restrict__ gcursor) {
    int t = threadIdx.x;
    if (t < NBUCK) gcursor[t] = off[t * 256];
}

// ---------------------------------------------------------------- pass 1: LDS-staged bucket binning
__global__ __launch_bounds__(256) void k_bucket(const int* __restrict__ src,
                                                const int* __restrict__ dst,
                                                int* __restrict__ gcursor,
                                                unsigned long long* __restrict__ pairs) {
    __shared__ int lcount[256];
    __shared__ int lstart[256];
    __shared__ int lresv[256];
    __shared__ unsigned long long stage[P1_CHUNK];   // 16 KB
    int t = threadIdx.x;
    int base = blockIdx.x * P1_CHUNK;
    int cnt = N_EDGES - base; if (cnt > P1_CHUNK) cnt = P1_CHUNK;

    lcount[t] = 0;
    __syncthreads();

    int my_s[P1_EPT], my_d[P1_EPT], my_b[P1_EPT];
#pragma unroll
    for (int j = 0; j < P1_EPT; ++j) {
        int idx = t + j * 256;
        if (idx < cnt) {
            my_s[j] = src[base + idx];
            my_d[j] = dst[base + idx];
            my_b[j] = my_d[j] >> 8;
            atomicAdd(&lcount[my_b[j]], 1);
        } else my_b[j] = -1;
    }
    __syncthreads();

    int v = lcount[t];
    lstart[t] = v;
    __syncthreads();
#pragma unroll
    for (int d = 1; d < 256; d <<= 1) {
        int nv = (t >= d) ? lstart[t - d] : 0;
        __syncthreads();
        lstart[t] += nv;
        __syncthreads();
    }
    int excl = lstart[t] - v;
    __syncthreads();
    lstart[t] = excl;
    lresv[t] = (t < NBUCK && v > 0) ? atomicAdd(&gcursor[t], v) : 0;
    lcount[t] = 0;
    __syncthreads();

#pragma unroll
    for (int j = 0; j < P1_EPT; ++j) {
        if (my_b[j] >= 0) {
            int lpos = lstart[my_b[j]] + atomicAdd(&lcount[my_b[j]], 1);
            stage[lpos] = ((unsigned long long)(unsigned)my_d[j] << 32) | (unsigned)my_s[j];
        }
    }
    __syncthreads();

    for (int sl = t; sl < cnt; sl += 256) {
        unsigned long long pr = stage[sl];
        int d_ = (int)(pr >> 32);
        int b_ = d_ >> 8;
        int g = lresv[b_] + (sl - lstart[b_]);
        pairs[g] = pr;
    }
}

// ---------------------------------------------------------------- pass 2: bucket -> final CSR
__global__ __launch_bounds__(256) void k_csr(const unsigned long long* __restrict__ pairs,
                                             const int* __restrict__ off,
                                             int* __restrict__ src_s) {
    __shared__ int cur[256];
    int b = blockIdx.x, t = threadIdx.x;
    int nb0 = b * 256;
    int nb1 = nb0 + 256; if (nb1 > N_NODES) nb1 = N_NODES;
    int e0 = off[nb0], e1 = off[nb1];
    cur[t] = 0;
    __syncthreads();
    for (int e = e0 + t; e < e1; e += 256) {
        unsigned long long pr = pairs[e];
        int d_ = (int)(pr >> 32);
        int s_ = (int)(pr & 0xffffffffu);
        int pos = off[d_] + atomicAdd(&cur[d_ & 255], 1);
        src_s[pos] = s_;
    }
}

// ---------------------------------------------------------------- fused 4-matrix MFMA GEMM
// A staged via coalesced load into XOR-swizzled LDS; W pre-permuted (coalesced B).
// q -> fp8 [node][128B]; k,v -> fp8 [node][k128B|v128B]; skip -> bf16.
__global__ __launch_bounds__(256) void k_gemm_fused(
    const __bf16* __restrict__ Xb,
    const __bf16* __restrict__ Wq, const __bf16* __restrict__ Wk,
    const __bf16* __restrict__ Wv, const __bf16* __restrict__ Wsk,
    const float* __restrict__ Bq, const float* __restrict__ Bk,
    const float* __restrict__ Bv, const float* __restrict__ Bs,
    unsigned char* __restrict__ Oq, unsigned char* __restrict__ Okv,
    __bf16* __restrict__ Osk) {
    __shared__ uint4 At[32][16];      // 8 KB, unit u stored at u ^ (row&15)
    __shared__ float lt[4][32][33];   // wave-private transpose tiles
    int t = threadIdx.x;
    int wsel = t >> 6, l = t & 63;
    int lo5 = l & 31, hi = l >> 5;
    int row0 = blockIdx.x * 32;

    const __bf16* W = (wsel == 0) ? Wq : (wsel == 1) ? Wk : (wsel == 2) ? Wv : Wsk;
    const float*  B = (wsel == 0) ? Bq : (wsel == 1) ? Bk : (wsel == 2) ? Bv : Bs;

    // ---- stage A: block reads 8KB linearly, swizzled LDS store
    {
        int r = t >> 3;                   // 0..31
        int u0 = (t & 7) * 2;             // 0,2,..,14
        int grow = row0 + r;
        uint4 a0 = {}, a1 = {};
        if (grow < N_NODES) {
            const uint4* gp = (const uint4*)(Xb + (size_t)grow * DIM);
            a0 = gp[u0]; a1 = gp[u0 + 1];
        }
        At[r][u0 ^ (r & 15)]       = a0;
        At[r][(u0 + 1) ^ (r & 15)] = a1;
    }
    __syncthreads();

    // ---- A fragments from LDS
    bf16x8 a[8];
#pragma unroll
    for (int kt = 0; kt < 8; ++kt)
        a[kt] = *(const bf16x8*)&At[lo5][(kt * 2 + hi) ^ (lo5 & 15)];

    int rr = l >> 1, h = l & 1;           // readback: row rr, 16-col half h
    int grow = row0 + rr;
    bool rok = (grow < N_NODES);

#pragma unroll
    for (int ct = 0; ct < 4; ++ct) {
        int col0 = ct * 32;
        const bf16x8* bp = (const bf16x8*)W + (size_t)(ct * 8) * 64 + l;  // coalesced
        f32x16 acc0 = {}, acc1 = {};
#pragma unroll
        for (int kt = 0; kt < 4; ++kt) {
            acc0 = __builtin_amdgcn_mfma_f32_32x32x16_bf16(a[kt],     bp[(size_t)kt * 64],       acc0, 0, 0, 0);
            acc1 = __builtin_amdgcn_mfma_f32_32x32x16_bf16(a[kt + 4], bp[(size_t)(kt + 4) * 64], acc1, 0, 0, 0);
        }
        f32x16 acc = acc0 + acc1;

        float bias = B[col0 + lo5];
#pragma unroll
        for (int r = 0; r < 16; ++r) {
            int rl = (r & 3) + 8 * (r >> 2) + 4 * hi;
            lt[wsel][rl][lo5] = acc[r] + bias;
        }
        __syncthreads();

        float vals[16];
#pragma unroll
        for (int j = 0; j < 16; ++j) vals[j] = lt[wsel][rr][h * 16 + j];

        if (rok) {
            int gcol = col0 + h * 16;
            if (wsel == 3) {
                bf16x8 o0, o1;
#pragma unroll
                for (int j = 0; j < 8; ++j) { o0[j] = (__bf16)vals[j]; o1[j] = (__bf16)vals[8 + j]; }
                bf16x8* orow = (bf16x8*)(Osk + (size_t)grow * DIM + gcol);
                orow[0] = o0; orow[1] = o1;
            } else if (wsel == 0) {
                uint4 pk = pack16_fp8(vals);
                *(uint4*)(Oq + (size_t)grow * 128 + gcol) = pk;
            } else {
                int coff = (wsel == 2) ? 128 : 0;   // k at +0, v at +128 bytes
                uint4 pk = pack16_fp8(vals);
                *(uint4*)(Okv + (size_t)grow * 256 + coff + gcol) = pk;
            }
        }
        __syncthreads();   // protect LDS tile before next ct overwrites
    }
}

// ---------------------------------------------------------------- fused alpha + softmax + aggregate (+skip+relu)
// One node per WAVE; 4x16-lane groups, 2-edge unroll, fp8 q/k/v via packed HW cvt,
// packed f32 math, no-max softmax. Output: bf16 state only.
__global__ __launch_bounds__(256) void k_edge_fused(const unsigned char* __restrict__ q,
                                                    const unsigned char* __restrict__ kv,
                                                    const __bf16* __restrict__ skip,
                                                    const int* __restrict__ src_s,
                                                    const int* __restrict__ off,
                                                    __bf16* __restrict__ xb) {
    int t = threadIdx.x;
    int wave = t >> 6, l = t & 63;
    int n = blockIdx.x * 4 + wave;               // 50000 = 12500 * 4
    if (n >= N_NODES) return;
    int g = l >> 4, gl = l & 15;                 // 4 groups of 16 lanes
    int start = off[n], end = off[n + 1];

    const float S = 0.08838834764831845f;        // 1/sqrt(128), folded into q
    f32x2 qf[4];
    {
        U8 qu; qu.u = *(const uint2*)(q + (size_t)n * 128 + gl * 8);
        cvt8_pk(qu, qf);
        f32x2 s2; s2[0] = S; s2[1] = S;
#pragma unroll
        for (int j = 0; j < 4; ++j) qf[j] *= s2;
    }

    float denom = 0.f;
    f32x2 facc[4] = {};

    for (int e = start + g; e < end; e += 8) {   // this group's edges, 2 per iter
        int s0 = src_s[e];
        bool h1 = (e + 4 < end);
        int s1 = h1 ? src_s[e + 4] : s0;         // dummy (w1 forced to 0)
        const unsigned char* r0 = kv + (size_t)s0 * 256 + gl * 8;
        const unsigned char* r1 = kv + (size_t)s1 * 256 + gl * 8;
        U8 k0u, k1u, v0u, v1u;
        k0u.u = *(const uint2*)(r0);
        k1u.u = *(const uint2*)(r1);
        v0u.u = *(const uint2*)(r0 + 128);
        v1u.u = *(const uint2*)(r1 + 128);

        f32x2 k0f[4], k1f[4];
        cvt8_pk(k0u, k0f);
        cvt8_pk(k1u, k1f);
        f32x2 d0 = qf[0] * k0f[0];
        f32x2 d1 = qf[0] * k1f[0];
        d0 += qf[1] * k0f[1];  d1 += qf[1] * k1f[1];
        d0 += qf[2] * k0f[2];  d1 += qf[2] * k1f[2];
        d0 += qf[3] * k0f[3];  d1 += qf[3] * k1f[3];
        float p0 = d0[0] + d0[1];
        float p1 = d1[0] + d1[1];
        p0 += __shfl_xor(p0, 8, 16);  p1 += __shfl_xor(p1, 8, 16);
        p0 += __shfl_xor(p0, 4, 16);  p1 += __shfl_xor(p1, 4, 16);
        p0 += __shfl_xor(p0, 2, 16);  p1 += __shfl_xor(p1, 2, 16);
        p0 += __shfl_xor(p0, 1, 16);  p1 += __shfl_xor(p1, 1, 16);
        p0 = fminf(p0, 80.f);                    // overflow insurance only
        p1 = h1 ? fminf(p1, 80.f) : -INFINITY;

        float w0 = __expf(p0);
        float w1 = __expf(p1);                   // exp(-inf) = 0 kills the tail slot
        denom += w0 + w1;

        f32x2 v0f[4], v1f[4];
        cvt8_pk(v0u, v0f);
        cvt8_pk(v1u, v1f);
        f32x2 w02; w02[0] = w0; w02[1] = w0;
        f32x2 w12; w12[0] = w1; w12[1] = w1;
#pragma unroll
        for (int j = 0; j < 4; ++j)
            facc[j] += w02 * v0f[j] + w12 * v1f[j];
    }

    // merge the 4 groups: plain adds
#pragma unroll
    for (int dlt = 16; dlt <= 32; dlt <<= 1) {
        denom += __shfl_xor(denom, dlt, 64);
#pragma unroll
        for (int j = 0; j < 4; ++j) {
            f32x2 o;
            o[0] = __shfl_xor(facc[j][0], dlt, 64);
            o[1] = __shfl_xor(facc[j][1], dlt, 64);
            facc[j] += o;
        }
    }
    float inv = (denom > 0.f) ? 1.f / denom : 0.f;

    if (g == 0) {
        bf16x8 sk = *(const bf16x8*)(skip + (size_t)n * DIM + gl * 8);
        bf16x8 ob;
#pragma unroll
        for (int j = 0; j < 8; ++j) {
            float f = facc[j >> 1][j & 1];
            float val = fmaxf((float)sk[j] + f * inv, 0.f);
            ob[j] = (__bf16)val;
        }
        *(bf16x8*)(xb + (size_t)n * DIM + gl * 8) = ob;
    }
}

// ---------------------------------------------------------------- mean pool (reads bf16 state)
__global__ __launch_bounds__(256) void k_pool(const __bf16* __restrict__ x,
                                              const int* __restrict__ batch,
                                              float* __restrict__ out) {
    __shared__ float sacc[4][DIM];
    int g = blockIdx.x;
    int t = threadIdx.x;
    int w = t >> 6, l = t & 63;
    int lo = 0, hi = N_NODES;
    while (lo < hi) { int mid = (lo + hi) >> 1; if (batch[mid] < g) lo = mid + 1; else hi = mid; }
    int s0 = lo;
    hi = N_NODES;
    while (lo < hi) { int mid = (lo + hi) >> 1; if (batch[mid] < g + 1) lo = mid + 1; else hi = mid; }
    int s1 = lo;
    float a0 = 0.f, a1 = 0.f;
    for (int n = s0 + w; n < s1; n += 4) {
        const __bf16* xr = x + (size_t)n * DIM + l * 2;
        a0 += (float)xr[0]; a1 += (float)xr[1];
    }
    sacc[w][l * 2] = a0; sacc[w][l * 2 + 1] = a1;
    __syncthreads();
    if (t < DIM) {
        float s = sacc[0][t] + sacc[1][t] + sacc[2][t] + sacc[3][t];
        int cnt = s1 - s0;
        out[(size_t)g * DIM + t] = s / (float)((cnt > 0) ? cnt : 1);
    }
}

// ----------------------------------------------------------------
extern "C" void kernel_launch(void* const* d_in, const int* in_sizes, int n_in,
                              void* d_out, int out_size, void* d_ws, size_t ws_size,
                              hipStream_t stream) {
    const float* x0   = (const float*)d_in[0];
    const int*  eidx  = (const int*)d_in[1];
    const int*  batch = (const int*)d_in[2];
    const float* Wq = (const float*)d_in[3];
    const float* bq = (const float*)d_in[4];
    const float* Wk = (const float*)d_in[5];
    const float* bk = (const float*)d_in[6];
    const float* Wv = (const float*)d_in[7];
    const float* bv = (const float*)d_in[8];
    const float* Ws = (const float*)d_in[9];
    const float* bs = (const float*)d_in[10];
    float* out = (float*)d_out;

    const int* src = eidx;
    const int* dst = eidx + N_EDGES;

    char* ws = (char*)d_ws;
    size_t p = 0;
    auto alloc = [&](size_t bytes) -> void* {
        void* r = ws + p;
        p = (p + bytes + 255) & ~(size_t)255;
        return r;
    };
    int*    off    = (int*)alloc((N_NODES + 1) * sizeof(int));
    int*    cnt    = (int*)alloc(N_NODES * sizeof(int));
    int*    bsum   = (int*)alloc(256 * sizeof(int));
    int*    boff   = (int*)alloc(256 * sizeof(int));
    int*    gcur   = (int*)alloc(256 * sizeof(int));
    int*    src_s  = (int*)alloc(N_EDGES * sizeof(int));
    unsigned long long* prs = (unsigned long long*)alloc((size_t)N_EDGES * 8);
    __bf16* Xb     = (__bf16*)alloc((size_t)N_NODES * DIM * sizeof(__bf16));
    unsigned char* qb  = (unsigned char*)alloc((size_t)N_NODES * 128);
    unsigned char* kvb = (unsigned char*)alloc((size_t)N_NODES * 256);
    __bf16* skb    = (__bf16*)alloc((size_t)N_NODES * DIM * sizeof(__bf16));
    __bf16* Wqb    = (__bf16*)alloc((size_t)NLAYERS * DIM * DIM * sizeof(__bf16));
    __bf16* Wkb    = (__bf16*)alloc((size_t)NLAYERS * DIM * DIM * sizeof(__bf16));
    __bf16* Wvb    = (__bf16*)alloc((size_t)NLAYERS * DIM * DIM * sizeof(__bf16));
    __bf16* Wsb    = (__bf16*)alloc((size_t)NLAYERS * DIM * DIM * sizeof(__bf16));

    // ---- casts (x linear; W cast+permute into fragment order)
    {
        int nx = N_NODES * DIM;
        k_cast<<<(nx / 8 + 255) / 256, 256, 0, stream>>>(x0, Xb, nx);
        dim3 gw((NLAYERS * 2048 + 255) / 256, 4);
        k_castW<<<gw, 256, 0, stream>>>(Wq, Wk, Wv, Ws, Wqb, Wkb, Wvb, Wsb);
    }

    // ---- build CSR (degree -> scan -> LDS-staged 2-pass bucket sort)
    hipMemsetAsync(cnt, 0, N_NODES * sizeof(int), stream);
    k_degree<<<(N_EDGES + 255) / 256, 256, 0, stream>>>(dst, cnt);
    k_scan1<<<SCAN_NB, 256, 0, stream>>>(cnt, off, bsum);
    k_scan2<<<1, 256, 0, stream>>>(bsum, boff, off + N_NODES);
    k_scan3<<<SCAN_NB, 256, 0, stream>>>(off, boff);
    k_ginit<<<1, 256, 0, stream>>>(off, gcur);
    k_bucket<<<P1_NB, 256, 0, stream>>>(src, dst, gcur, prs);
    k_csr<<<NBUCK, 256, 0, stream>>>(prs, off, src_s);

    // ---- layers
    for (int l = 0; l < NLAYERS; ++l) {
        const __bf16* wq = Wqb + (size_t)l * DIM * DIM;
        const __bf16* wk = Wkb + (size_t)l * DIM * DIM;
        const __bf16* wv = Wvb + (size_t)l * DIM * DIM;
        const __bf16* wsk = Wsb + (size_t)l * DIM * DIM;
        const float* biq = bq + (size_t)l * DIM;
        const float* bik = bk + (size_t)l * DIM;
        const float* biv = bv + (size_t)l * DIM;
        const float* bis = bs + (size_t)l * DIM;

        k_gemm_fused<<<(N_NODES + 31) / 32, 256, 0, stream>>>(Xb, wq, wk, wv, wsk,
                                                              biq, bik, biv, bis,
                                                              qb, kvb, skb);
        k_edge_fused<<<(N_NODES + 3) / 4, 256, 0, stream>>>(qb, kvb, skb, src_s, off, Xb);
    }

    // ---- mean pool
    k_pool<<<NGRAPH, 256, 0, stream>>>(Xb, batch, out);
}